// Round 1
// baseline (708.355 us; speedup 1.0000x reference)
//
#include <hip/hip_runtime.h>
#include <hip/hip_bf16.h>
#include <math.h>

// ---------------------------------------------------------------------------
// PMLP_GCN forward:  3x (GEMM -> GCN-agg[+bias]) with BN+ReLU between,
// log_softmax at the end.  N=50000 E=640000 IN=500 HID=128 OUT=64, f32.
// Baseline: gather-CSR aggregation (built per call), f32 tiled GEMM.
// ---------------------------------------------------------------------------

#define EPS_BN 1e-5f

// ---------------- graph prep ----------------

__global__ void count_k(const int* __restrict__ src, const int* __restrict__ dst,
                        int* __restrict__ cnt, int E) {
    int e = blockIdx.x * 256 + threadIdx.x;
    if (e >= E) return;
    int s = src[e], d = dst[e];
    if (s != d) atomicAdd(&cnt[d], 1);
}

__global__ void prep_k(const int* __restrict__ cnt, float* __restrict__ dinv,
                       float* __restrict__ invdeg, int n) {
    int i = blockIdx.x * 256 + threadIdx.x;
    if (i >= n) return;
    float deg = (float)cnt[i] + 1.0f;   // +1 for added self loop
    dinv[i]   = rsqrtf(deg);
    invdeg[i] = 1.0f / deg;
}

// 3-kernel exclusive prefix scan over cnt[n] -> row_start
__global__ void scan1_k(const int* __restrict__ cnt, int* __restrict__ within,
                        int* __restrict__ btot, int n) {
    __shared__ int s[512];
    int tid = threadIdx.x;
    int i = blockIdx.x * 512 + tid;
    int val = (i < n) ? cnt[i] : 0;
    s[tid] = val;
    __syncthreads();
    for (int off = 1; off < 512; off <<= 1) {
        int v = (tid >= off) ? s[tid - off] : 0;
        __syncthreads();
        s[tid] += v;
        __syncthreads();
    }
    if (i < n) within[i] = s[tid] - val;   // exclusive
    if (tid == 511) btot[blockIdx.x] = s[511];
}

__global__ void scan2_k(const int* __restrict__ btot, int* __restrict__ boff, int nblk) {
    if (threadIdx.x == 0) {
        int run = 0;
        for (int b = 0; b < nblk; ++b) { boff[b] = run; run += btot[b]; }
    }
}

__global__ void scan3_k(const int* __restrict__ within, const int* __restrict__ boff,
                        int* __restrict__ row_start, int* __restrict__ cursor, int n) {
    int i = blockIdx.x * 256 + threadIdx.x;
    if (i >= n) return;
    int v = within[i] + boff[i >> 9];
    row_start[i] = v;
    cursor[i]    = v;
}

__global__ void fill_k(const int* __restrict__ src, const int* __restrict__ dst,
                       const float* __restrict__ dinv, int* __restrict__ cursor,
                       int* __restrict__ eidx, float* __restrict__ ew, int E) {
    int e = blockIdx.x * 256 + threadIdx.x;
    if (e >= E) return;
    int s = src[e], d = dst[e];
    if (s == d) return;
    int pos = atomicAdd(&cursor[d], 1);
    eidx[pos] = s;
    ew[pos]   = dinv[s] * dinv[d];
}

// ---------------- GEMM: C[M,NC] = A[M,K] * W[NC,K]^T ----------------
// 128-row x NC-col tile per 256-thread block; 8 x (NC/16) register tile.
// LDS padded to 33 floats/row; thread->col map stride 16 => conflict-free.

template <int NC>
__global__ __launch_bounds__(256) void gemm_k(const float* __restrict__ A,
                                              const float* __restrict__ W,
                                              float* __restrict__ C, int M, int K) {
    constexpr int CN = NC / 16;            // cols per thread
    __shared__ float As[128][33];
    __shared__ float Ws[NC][33];
    const int tid = threadIdx.x;
    const int tx = tid & 15, ty = tid >> 4;
    const int row0 = blockIdx.x * 128;

    float acc[8][CN];
    for (int r = 0; r < 8; ++r)
        for (int c = 0; c < CN; ++c) acc[r][c] = 0.f;

    for (int k0 = 0; k0 < K; k0 += 32) {
        for (int idx = tid; idx < 128 * 32; idx += 256) {
            int r = idx >> 5, kk = idx & 31;
            int gr = row0 + r, gk = k0 + kk;
            As[r][kk] = (gr < M && gk < K) ? A[gr * K + gk] : 0.f;
        }
        for (int idx = tid; idx < NC * 32; idx += 256) {
            int r = idx >> 5, kk = idx & 31;
            int gk = k0 + kk;
            Ws[r][kk] = (gk < K) ? W[r * K + gk] : 0.f;
        }
        __syncthreads();
        #pragma unroll 4
        for (int kk = 0; kk < 32; ++kk) {
            float a[8], b[CN];
            #pragma unroll
            for (int r = 0; r < 8; ++r) a[r] = As[ty + 16 * r][kk];
            #pragma unroll
            for (int c = 0; c < CN; ++c) b[c] = Ws[tx + 16 * c][kk];
            #pragma unroll
            for (int r = 0; r < 8; ++r)
                #pragma unroll
                for (int c = 0; c < CN; ++c)
                    acc[r][c] = fmaf(a[r], b[c], acc[r][c]);
        }
        __syncthreads();
    }
    for (int r = 0; r < 8; ++r) {
        int gr = row0 + ty + 16 * r;
        if (gr >= M) continue;
        for (int c = 0; c < CN; ++c)
            C[gr * NC + tx + 16 * c] = acc[r][c];
    }
}

// ---------------- GCN aggregation (gather over CSR) ----------------
// out[i] = sum_{e: dst=i} w_e * h[src_e] + invdeg[i]*h[i] + bias

template <int NF>
__global__ void agg_k(const float* __restrict__ h, const float* __restrict__ invdeg,
                      const int* __restrict__ row_start, const int* __restrict__ cnt,
                      const int* __restrict__ eidx, const float* __restrict__ ew,
                      const float* __restrict__ bias, float* __restrict__ out, int n) {
    int i = blockIdx.x;
    if (i >= n) return;
    int f = threadIdx.x;
    float acc = invdeg[i] * h[i * NF + f] + bias[f];
    int st = row_start[i], en = st + cnt[i];
    for (int p = st; p < en; ++p) {
        int s   = eidx[p];
        float w = ew[p];
        acc = fmaf(w, h[s * NF + f], acc);
    }
    out[i * NF + f] = acc;
}

// ---------------- BatchNorm (affine=False) + ReLU ----------------

__global__ void stats_k(const float* __restrict__ a, float* __restrict__ gsum,
                        float* __restrict__ gsq, int n) {
    __shared__ float ls[256], lq[256];
    int tid = threadIdx.x;
    int c = tid & 127, g = tid >> 7;
    float s = 0.f, q = 0.f;
    for (int row = blockIdx.x * 2 + g; row < n; row += gridDim.x * 2) {
        float v = a[row * 128 + c];
        s += v; q += v * v;
    }
    ls[tid] = s; lq[tid] = q;
    __syncthreads();
    if (tid < 128) {
        atomicAdd(&gsum[c], ls[tid] + ls[tid + 128]);
        atomicAdd(&gsq[c],  lq[tid] + lq[tid + 128]);
    }
}

__global__ void finalize_k(const float* __restrict__ gsum, const float* __restrict__ gsq,
                           float* __restrict__ scale, float* __restrict__ shift, int n) {
    int c = threadIdx.x;   // 128
    float mean = gsum[c] / (float)n;
    float var  = gsq[c] / (float)n - mean * mean;
    float sc   = rsqrtf(var + EPS_BN);
    scale[c] = sc;
    shift[c] = -mean * sc;
}

__global__ void norm_k(float* __restrict__ a, const float* __restrict__ scale,
                       const float* __restrict__ shift, int total4) {
    int idx = blockIdx.x * 256 + threadIdx.x;
    if (idx >= total4) return;
    float4 v = ((const float4*)a)[idx];
    int c0 = (idx & 31) * 4;
    v.x = fmaxf(0.f, fmaf(v.x, scale[c0 + 0], shift[c0 + 0]));
    v.y = fmaxf(0.f, fmaf(v.y, scale[c0 + 1], shift[c0 + 1]));
    v.z = fmaxf(0.f, fmaf(v.z, scale[c0 + 2], shift[c0 + 2]));
    v.w = fmaxf(0.f, fmaf(v.w, scale[c0 + 3], shift[c0 + 3]));
    ((float4*)a)[idx] = v;
}

// ---------------- log_softmax over 64 cols: one wave per row ----------------

__global__ void lsm_k(float* __restrict__ out, int n) {
    int lane = threadIdx.x & 63;
    int row = blockIdx.x * 4 + (threadIdx.x >> 6);
    if (row >= n) return;
    float v = out[row * 64 + lane];
    float m = v;
    #pragma unroll
    for (int d = 32; d >= 1; d >>= 1) m = fmaxf(m, __shfl_xor(m, d, 64));
    float e = __expf(v - m);
    float s = e;
    #pragma unroll
    for (int d = 32; d >= 1; d >>= 1) s += __shfl_xor(s, d, 64);
    out[row * 64 + lane] = v - m - __logf(s);
}

// ---------------------------------------------------------------------------

extern "C" void kernel_launch(void* const* d_in, const int* in_sizes, int n_in,
                              void* d_out, int out_size, void* d_ws, size_t ws_size,
                              hipStream_t stream) {
    const float* x  = (const float*)d_in[0];
    const int*   ei = (const int*)d_in[1];
    const float* W0 = (const float*)d_in[2];
    const float* b0 = (const float*)d_in[3];
    const float* W1 = (const float*)d_in[4];
    const float* b1 = (const float*)d_in[5];
    const float* W2 = (const float*)d_in[6];
    const float* b2 = (const float*)d_in[7];

    const int IN = 500, HID = 128, OUTF = 64;
    const int n = in_sizes[0] / IN;      // 50000
    const int E = in_sizes[1] / 2;       // 640000
    const int* src = ei;
    const int* dst = ei + E;

    // ---- workspace bump allocator (256B aligned) ----
    char* p = (char*)d_ws;
    auto alloc = [&](size_t bytes) -> void* {
        char* r = p;
        p += (bytes + 255) & ~(size_t)255;
        return (void*)r;
    };
    float* hb1      = (float*)alloc((size_t)n * 128 * 4);
    float* hb2      = (float*)alloc((size_t)n * 128 * 4);
    int*   deg_cnt  = (int*)alloc((size_t)n * 4);
    float* dinv     = (float*)alloc((size_t)n * 4);
    float* invdeg   = (float*)alloc((size_t)n * 4);
    int*   row_st   = (int*)alloc((size_t)n * 4);
    int*   cursor   = (int*)alloc((size_t)n * 4);
    int*   within   = (int*)alloc((size_t)n * 4);
    int*   btot     = (int*)alloc(256 * 4);
    int*   boff     = (int*)alloc(256 * 4);
    int*   eidx     = (int*)alloc((size_t)E * 4);
    float* ew       = (float*)alloc((size_t)E * 4);
    float* gsum     = (float*)alloc(128 * 4);   // gsum+gsq contiguous: one memset
    float* gsq      = (float*)alloc(128 * 4);
    float* scale    = (float*)alloc(128 * 4);
    float* shift    = (float*)alloc(128 * 4);
    (void)ws_size; (void)n_in; (void)out_size;

    float* out = (float*)d_out;

    const int gE = (E + 255) / 256;
    const int gN = (n + 255) / 256;
    const int nblk = (n + 511) / 512;
    const int gM = (n + 127) / 128;

    // ---- graph prep (once per call) ----
    hipMemsetAsync(deg_cnt, 0, (size_t)n * 4, stream);
    count_k<<<gE, 256, 0, stream>>>(src, dst, deg_cnt, E);
    prep_k<<<gN, 256, 0, stream>>>(deg_cnt, dinv, invdeg, n);
    scan1_k<<<nblk, 512, 0, stream>>>(deg_cnt, within, btot, n);
    scan2_k<<<1, 64, 0, stream>>>(btot, boff, nblk);
    scan3_k<<<gN, 256, 0, stream>>>(within, boff, row_st, cursor, n);
    fill_k<<<gE, 256, 0, stream>>>(src, dst, dinv, cursor, eidx, ew, E);

    // ---- layer 0 ----
    gemm_k<128><<<gM, 256, 0, stream>>>(x, W0, hb1, n, IN);
    agg_k<128><<<n, 128, 0, stream>>>(hb1, invdeg, row_st, deg_cnt, eidx, ew, b0, hb2, n);
    hipMemsetAsync(gsum, 0, 256 * 4, stream);
    stats_k<<<256, 256, 0, stream>>>(hb2, gsum, gsq, n);
    finalize_k<<<1, 128, 0, stream>>>(gsum, gsq, scale, shift, n);
    norm_k<<<(n * 32 + 255) / 256, 256, 0, stream>>>(hb2, scale, shift, n * 32);

    // ---- layer 1 ----
    gemm_k<128><<<gM, 256, 0, stream>>>(hb2, W1, hb1, n, HID);
    agg_k<128><<<n, 128, 0, stream>>>(hb1, invdeg, row_st, deg_cnt, eidx, ew, b1, hb2, n);
    hipMemsetAsync(gsum, 0, 256 * 4, stream);
    stats_k<<<256, 256, 0, stream>>>(hb2, gsum, gsq, n);
    finalize_k<<<1, 128, 0, stream>>>(gsum, gsq, scale, shift, n);
    norm_k<<<(n * 32 + 255) / 256, 256, 0, stream>>>(hb2, scale, shift, n * 32);

    // ---- classifier ----
    gemm_k<64><<<gM, 256, 0, stream>>>(hb2, W2, hb1, n, HID);
    agg_k<64><<<n, 64, 0, stream>>>(hb1, invdeg, row_st, deg_cnt, eidx, ew, b2, out, n);
    lsm_k<<<(n + 3) / 4, 256, 0, stream>>>(out, n);
}

// Round 2
// 454.933 us; speedup vs baseline: 1.5571x; 1.5571x over previous
//
#include <hip/hip_runtime.h>
#include <hip/hip_bf16.h>
#include <math.h>

// ---------------------------------------------------------------------------
// PMLP_GCN forward:  3x (GEMM -> GCN-agg[+bias]) with BN+ReLU between,
// log_softmax at the end.  N=50000 E=640000 IN=500 HID=128 OUT=64, f32.
// R1: GEMMs moved to f16 MFMA (16x16x32), conversion fused into LDS staging.
// ---------------------------------------------------------------------------

#define EPS_BN 1e-5f

typedef __attribute__((ext_vector_type(8))) _Float16 f16x8;
typedef __attribute__((ext_vector_type(4))) _Float16 f16x4;
typedef __attribute__((ext_vector_type(4))) float    f32x4;

// ---------------- graph prep ----------------

__global__ void count_k(const int* __restrict__ src, const int* __restrict__ dst,
                        int* __restrict__ cnt, int E) {
    int e = blockIdx.x * 256 + threadIdx.x;
    if (e >= E) return;
    int s = src[e], d = dst[e];
    if (s != d) atomicAdd(&cnt[d], 1);
}

__global__ void prep_k(const int* __restrict__ cnt, float* __restrict__ dinv,
                       float* __restrict__ invdeg, int n) {
    int i = blockIdx.x * 256 + threadIdx.x;
    if (i >= n) return;
    float deg = (float)cnt[i] + 1.0f;   // +1 for added self loop
    dinv[i]   = rsqrtf(deg);
    invdeg[i] = 1.0f / deg;
}

// 3-kernel exclusive prefix scan over cnt[n] -> row_start
__global__ void scan1_k(const int* __restrict__ cnt, int* __restrict__ within,
                        int* __restrict__ btot, int n) {
    __shared__ int s[512];
    int tid = threadIdx.x;
    int i = blockIdx.x * 512 + tid;
    int val = (i < n) ? cnt[i] : 0;
    s[tid] = val;
    __syncthreads();
    for (int off = 1; off < 512; off <<= 1) {
        int v = (tid >= off) ? s[tid - off] : 0;
        __syncthreads();
        s[tid] += v;
        __syncthreads();
    }
    if (i < n) within[i] = s[tid] - val;   // exclusive
    if (tid == 511) btot[blockIdx.x] = s[511];
}

__global__ void scan2_k(const int* __restrict__ btot, int* __restrict__ boff, int nblk) {
    if (threadIdx.x == 0) {
        int run = 0;
        for (int b = 0; b < nblk; ++b) { boff[b] = run; run += btot[b]; }
    }
}

__global__ void scan3_k(const int* __restrict__ within, const int* __restrict__ boff,
                        int* __restrict__ row_start, int* __restrict__ cursor, int n) {
    int i = blockIdx.x * 256 + threadIdx.x;
    if (i >= n) return;
    int v = within[i] + boff[i >> 9];
    row_start[i] = v;
    cursor[i]    = v;
}

__global__ void fill_k(const int* __restrict__ src, const int* __restrict__ dst,
                       const float* __restrict__ dinv, int* __restrict__ cursor,
                       int* __restrict__ eidx, float* __restrict__ ew, int E) {
    int e = blockIdx.x * 256 + threadIdx.x;
    if (e >= E) return;
    int s = src[e], d = dst[e];
    if (s == d) return;
    int pos = atomicAdd(&cursor[d], 1);
    eidx[pos] = s;
    ew[pos]   = dinv[s] * dinv[d];
}

// ---------------- MFMA GEMM: C[M,NC] = A[M,K] * W[NC,K]^T ----------------
// f16 inputs (converted in staging), f32 accumulate.
// Block: 256 thr = 4 waves; tile 128 x NC; K-chunk 64.
// LDS rows: 64 f16 = 128 B stride, XOR-swizzled (byte ^= (row&7)<<4) so the
// stride-128B fragment reads (ds_read_b128) are 2-way max (free).

template <int NC, bool A_IS_F32>
__global__ __launch_bounds__(256) void mgemm_k(const void* __restrict__ Av,
                                               const float* __restrict__ W,
                                               float* __restrict__ C,
                                               int M, int K) {
    constexpr int CT = NC / 16;            // col tiles per wave
    __shared__ __align__(16) _Float16 As[128 * 64];
    __shared__ __align__(16) _Float16 Ws[NC * 64];

    const int tid  = threadIdx.x;
    const int lane = tid & 63, wave = tid >> 6;
    const int lrow = lane & 15, kg = lane >> 4;
    const int row0 = blockIdx.x * 128;

    f32x4 acc[2][CT] = {};

    const int nchunk = (K + 63) >> 6;
    for (int c0 = 0; c0 < nchunk; ++c0) {
        const int k0 = c0 * 64;
        // ---- stage A tile (128 x 64) ----
        if constexpr (A_IS_F32) {
            const float* A = (const float*)Av;
            #pragma unroll
            for (int it = 0; it < 8; ++it) {
                int idx  = tid + it * 256;
                int row  = idx >> 4, slot = idx & 15;     // 16 float4 slots/row
                int gr   = row0 + row, gk = k0 + slot * 4;
                float4 v = make_float4(0.f, 0.f, 0.f, 0.f);
                if (gr < M && gk < K)                      // K%4==0 -> all-or-none
                    v = *(const float4*)(A + (size_t)gr * K + gk);
                f16x4 h;
                h[0] = (_Float16)v.x; h[1] = (_Float16)v.y;
                h[2] = (_Float16)v.z; h[3] = (_Float16)v.w;
                int cb = (slot * 8) ^ ((row & 7) << 4);
                *(f16x4*)((char*)As + row * 128 + cb) = h;
            }
        } else {
            const _Float16* A = (const _Float16*)Av;
            #pragma unroll
            for (int it = 0; it < 4; ++it) {
                int idx = tid + it * 256;
                int row = idx >> 3, slot = idx & 7;        // 8x 16B slots/row
                int gr  = row0 + row, gk = k0 + slot * 8;
                uint4 v = make_uint4(0u, 0u, 0u, 0u);
                if (gr < M && gk < K)
                    v = *(const uint4*)(A + (size_t)gr * K + gk);
                int cb = (slot * 16) ^ ((row & 7) << 4);
                *(uint4*)((char*)As + row * 128 + cb) = v;
            }
        }
        // ---- stage W tile (NC x 64), W is f32 [NC][K] ----
        for (int idx = tid; idx < NC * 16; idx += 256) {
            int row = idx >> 4, slot = idx & 15;
            int gk  = k0 + slot * 4;
            float4 v = make_float4(0.f, 0.f, 0.f, 0.f);
            if (gk < K)
                v = *(const float4*)(W + (size_t)row * K + gk);
            f16x4 h;
            h[0] = (_Float16)v.x; h[1] = (_Float16)v.y;
            h[2] = (_Float16)v.z; h[3] = (_Float16)v.w;
            int cb = (slot * 8) ^ ((row & 7) << 4);
            *(f16x4*)((char*)Ws + row * 128 + cb) = h;
        }
        __syncthreads();

        #pragma unroll
        for (int ks = 0; ks < 2; ++ks) {
            const int cbase = ks * 64 + kg * 16;
            f16x8 af[2], bf[CT];
            #pragma unroll
            for (int rt = 0; rt < 2; ++rt) {
                int row = wave * 32 + rt * 16 + lrow;
                af[rt] = *(const f16x8*)((const char*)As + row * 128 +
                                         (cbase ^ ((row & 7) << 4)));
            }
            #pragma unroll
            for (int ct = 0; ct < CT; ++ct) {
                int row = ct * 16 + lrow;
                bf[ct] = *(const f16x8*)((const char*)Ws + row * 128 +
                                         (cbase ^ ((row & 7) << 4)));
            }
            #pragma unroll
            for (int rt = 0; rt < 2; ++rt)
                #pragma unroll
                for (int ct = 0; ct < CT; ++ct)
                    acc[rt][ct] = __builtin_amdgcn_mfma_f32_16x16x32_f16(
                        af[rt], bf[ct], acc[rt][ct], 0, 0, 0);
        }
        __syncthreads();
    }

    // ---- epilogue: D lane map col=lane&15, row=(lane>>4)*4+r ----
    #pragma unroll
    for (int rt = 0; rt < 2; ++rt) {
        #pragma unroll
        for (int r = 0; r < 4; ++r) {
            int grow = row0 + wave * 32 + rt * 16 + kg * 4 + r;
            if (grow >= M) continue;
            #pragma unroll
            for (int ct = 0; ct < CT; ++ct)
                C[(size_t)grow * NC + ct * 16 + lrow] = acc[rt][ct][r];
        }
    }
}

// ---------------- GCN aggregation (gather over CSR) ----------------
// out[i] = sum_{e: dst=i} w_e * h[src_e] + invdeg[i]*h[i] + bias

template <int NF>
__global__ void agg_k(const float* __restrict__ h, const float* __restrict__ invdeg,
                      const int* __restrict__ row_start, const int* __restrict__ cnt,
                      const int* __restrict__ eidx, const float* __restrict__ ew,
                      const float* __restrict__ bias, float* __restrict__ out, int n) {
    int i = blockIdx.x;
    if (i >= n) return;
    int f = threadIdx.x;
    float acc = invdeg[i] * h[i * NF + f] + bias[f];
    int st = row_start[i], en = st + cnt[i];
    for (int p = st; p < en; ++p) {
        int s   = eidx[p];
        float w = ew[p];
        acc = fmaf(w, h[s * NF + f], acc);
    }
    out[i * NF + f] = acc;
}

// ---------------- BatchNorm (affine=False) + ReLU ----------------

__global__ void stats_k(const float* __restrict__ a, float* __restrict__ gsum,
                        float* __restrict__ gsq, int n) {
    __shared__ float ls[256], lq[256];
    int tid = threadIdx.x;
    int c = tid & 127, g = tid >> 7;
    float s = 0.f, q = 0.f;
    for (int row = blockIdx.x * 2 + g; row < n; row += gridDim.x * 2) {
        float v = a[row * 128 + c];
        s += v; q += v * v;
    }
    ls[tid] = s; lq[tid] = q;
    __syncthreads();
    if (tid < 128) {
        atomicAdd(&gsum[c], ls[tid] + ls[tid + 128]);
        atomicAdd(&gsq[c],  lq[tid] + lq[tid + 128]);
    }
}

__global__ void finalize_k(const float* __restrict__ gsum, const float* __restrict__ gsq,
                           float* __restrict__ scale, float* __restrict__ shift, int n) {
    int c = threadIdx.x;   // 128
    float mean = gsum[c] / (float)n;
    float var  = gsq[c] / (float)n - mean * mean;
    float sc   = rsqrtf(var + EPS_BN);
    scale[c] = sc;
    shift[c] = -mean * sc;
}

// BN scale/shift + ReLU, f32 in -> f16 out (only consumer is the next GEMM)
__global__ void norm_k(const float* __restrict__ a, _Float16* __restrict__ o,
                       const float* __restrict__ scale, const float* __restrict__ shift,
                       int total4) {
    int idx = blockIdx.x * 256 + threadIdx.x;
    if (idx >= total4) return;
    float4 v = ((const float4*)a)[idx];
    int c0 = (idx & 31) * 4;
    f16x4 h;
    h[0] = (_Float16)fmaxf(0.f, fmaf(v.x, scale[c0 + 0], shift[c0 + 0]));
    h[1] = (_Float16)fmaxf(0.f, fmaf(v.y, scale[c0 + 1], shift[c0 + 1]));
    h[2] = (_Float16)fmaxf(0.f, fmaf(v.z, scale[c0 + 2], shift[c0 + 2]));
    h[3] = (_Float16)fmaxf(0.f, fmaf(v.w, scale[c0 + 3], shift[c0 + 3]));
    *(f16x4*)(o + (size_t)idx * 4) = h;
}

// ---------------- log_softmax over 64 cols: one wave per row ----------------

__global__ void lsm_k(float* __restrict__ out, int n) {
    int lane = threadIdx.x & 63;
    int row = blockIdx.x * 4 + (threadIdx.x >> 6);
    if (row >= n) return;
    float v = out[row * 64 + lane];
    float m = v;
    #pragma unroll
    for (int d = 32; d >= 1; d >>= 1) m = fmaxf(m, __shfl_xor(m, d, 64));
    float e = __expf(v - m);
    float s = e;
    #pragma unroll
    for (int d = 32; d >= 1; d >>= 1) s += __shfl_xor(s, d, 64);
    out[row * 64 + lane] = v - m - __logf(s);
}

// ---------------------------------------------------------------------------

extern "C" void kernel_launch(void* const* d_in, const int* in_sizes, int n_in,
                              void* d_out, int out_size, void* d_ws, size_t ws_size,
                              hipStream_t stream) {
    const float* x  = (const float*)d_in[0];
    const int*   ei = (const int*)d_in[1];
    const float* W0 = (const float*)d_in[2];
    const float* b0 = (const float*)d_in[3];
    const float* W1 = (const float*)d_in[4];
    const float* b1 = (const float*)d_in[5];
    const float* W2 = (const float*)d_in[6];
    const float* b2 = (const float*)d_in[7];

    const int IN = 500;
    const int n = in_sizes[0] / IN;      // 50000
    const int E = in_sizes[1] / 2;       // 640000
    const int* src = ei;
    const int* dst = ei + E;

    // ---- workspace bump allocator (256B aligned) ----
    char* p = (char*)d_ws;
    auto alloc = [&](size_t bytes) -> void* {
        char* r = p;
        p += (bytes + 255) & ~(size_t)255;
        return (void*)r;
    };
    float*     hb1     = (float*)alloc((size_t)n * 128 * 4);   // GEMM out / agg in
    float*     hb2     = (float*)alloc((size_t)n * 128 * 4);   // agg out / BN in
    _Float16*  hb2h    = (_Float16*)alloc((size_t)n * 128 * 2);// BN out / GEMM in
    int*   deg_cnt  = (int*)alloc((size_t)n * 4);
    float* dinv     = (float*)alloc((size_t)n * 4);
    float* invdeg   = (float*)alloc((size_t)n * 4);
    int*   row_st   = (int*)alloc((size_t)n * 4);
    int*   cursor   = (int*)alloc((size_t)n * 4);
    int*   within   = (int*)alloc((size_t)n * 4);
    int*   btot     = (int*)alloc(256 * 4);
    int*   boff     = (int*)alloc(256 * 4);
    int*   eidx     = (int*)alloc((size_t)E * 4);
    float* ew       = (float*)alloc((size_t)E * 4);
    float* gsum     = (float*)alloc(128 * 4);   // gsum+gsq contiguous: one memset
    float* gsq      = (float*)alloc(128 * 4);
    float* scale    = (float*)alloc(128 * 4);
    float* shift    = (float*)alloc(128 * 4);
    (void)ws_size; (void)n_in; (void)out_size;

    float* out = (float*)d_out;

    const int gE = (E + 255) / 256;
    const int gN = (n + 255) / 256;
    const int nblk = (n + 511) / 512;
    const int gM = (n + 127) / 128;

    // ---- graph prep (once per call) ----
    hipMemsetAsync(deg_cnt, 0, (size_t)n * 4, stream);
    count_k<<<gE, 256, 0, stream>>>(src, dst, deg_cnt, E);
    prep_k<<<gN, 256, 0, stream>>>(deg_cnt, dinv, invdeg, n);
    scan1_k<<<nblk, 512, 0, stream>>>(deg_cnt, within, btot, n);
    scan2_k<<<1, 64, 0, stream>>>(btot, boff, nblk);
    scan3_k<<<gN, 256, 0, stream>>>(within, boff, row_st, cursor, n);
    fill_k<<<gE, 256, 0, stream>>>(src, dst, dinv, cursor, eidx, ew, E);

    // ---- layer 0 ----
    mgemm_k<128, true><<<gM, 256, 0, stream>>>(x, W0, hb1, n, IN);
    agg_k<128><<<n, 128, 0, stream>>>(hb1, invdeg, row_st, deg_cnt, eidx, ew, b0, hb2, n);
    hipMemsetAsync(gsum, 0, 256 * 4, stream);
    stats_k<<<256, 256, 0, stream>>>(hb2, gsum, gsq, n);
    finalize_k<<<1, 128, 0, stream>>>(gsum, gsq, scale, shift, n);
    norm_k<<<(n * 32 + 255) / 256, 256, 0, stream>>>(hb2, hb2h, scale, shift, n * 32);

    // ---- layer 1 ----
    mgemm_k<128, false><<<gM, 256, 0, stream>>>(hb2h, W1, hb1, n, 128);
    agg_k<128><<<n, 128, 0, stream>>>(hb1, invdeg, row_st, deg_cnt, eidx, ew, b1, hb2, n);
    hipMemsetAsync(gsum, 0, 256 * 4, stream);
    stats_k<<<256, 256, 0, stream>>>(hb2, gsum, gsq, n);
    finalize_k<<<1, 128, 0, stream>>>(gsum, gsq, scale, shift, n);
    norm_k<<<(n * 32 + 255) / 256, 256, 0, stream>>>(hb2, hb2h, scale, shift, n * 32);

    // ---- classifier ----
    mgemm_k<64, false><<<gM, 256, 0, stream>>>(hb2h, W2, hb1, n, 128);
    agg_k<64><<<n, 64, 0, stream>>>(hb1, invdeg, row_st, deg_cnt, eidx, ew, b2, out, n);
    lsm_k<<<(n + 3) / 4, 256, 0, stream>>>(out, n);
}

// Round 3
// 358.153 us; speedup vs baseline: 1.9778x; 1.2702x over previous
//
#include <hip/hip_runtime.h>
#include <hip/hip_bf16.h>
#include <math.h>

// ---------------------------------------------------------------------------
// PMLP_GCN forward:  3x (GEMM -> GCN-agg[+bias]) with BN+ReLU between,
// log_softmax at the end.  N=50000 E=640000 IN=500 HID=128 OUT=64, f32.
// R2: GEMM 64-row tiles (grid 782, occupancy fix); all GEMMs emit f16;
//     agg gathers f16 rows, one wave per node, 2-edge unroll.
// ---------------------------------------------------------------------------

#define EPS_BN 1e-5f

typedef __attribute__((ext_vector_type(8))) _Float16 f16x8;
typedef __attribute__((ext_vector_type(4))) _Float16 f16x4;
typedef __attribute__((ext_vector_type(2))) _Float16 f16x2;
typedef __attribute__((ext_vector_type(4))) float    f32x4;

// ---------------- graph prep ----------------

__global__ void count_k(const int* __restrict__ src, const int* __restrict__ dst,
                        int* __restrict__ cnt, int E) {
    int e = blockIdx.x * 256 + threadIdx.x;
    if (e >= E) return;
    int s = src[e], d = dst[e];
    if (s != d) atomicAdd(&cnt[d], 1);
}

__global__ void prep_k(const int* __restrict__ cnt, float* __restrict__ dinv,
                       float* __restrict__ invdeg, int n) {
    int i = blockIdx.x * 256 + threadIdx.x;
    if (i >= n) return;
    float deg = (float)cnt[i] + 1.0f;   // +1 for added self loop
    dinv[i]   = rsqrtf(deg);
    invdeg[i] = 1.0f / deg;
}

// 3-kernel exclusive prefix scan over cnt[n] -> row_start
__global__ void scan1_k(const int* __restrict__ cnt, int* __restrict__ within,
                        int* __restrict__ btot, int n) {
    __shared__ int s[512];
    int tid = threadIdx.x;
    int i = blockIdx.x * 512 + tid;
    int val = (i < n) ? cnt[i] : 0;
    s[tid] = val;
    __syncthreads();
    for (int off = 1; off < 512; off <<= 1) {
        int v = (tid >= off) ? s[tid - off] : 0;
        __syncthreads();
        s[tid] += v;
        __syncthreads();
    }
    if (i < n) within[i] = s[tid] - val;   // exclusive
    if (tid == 511) btot[blockIdx.x] = s[511];
}

__global__ void scan2_k(const int* __restrict__ btot, int* __restrict__ boff, int nblk) {
    if (threadIdx.x == 0) {
        int run = 0;
        for (int b = 0; b < nblk; ++b) { boff[b] = run; run += btot[b]; }
    }
}

__global__ void scan3_k(const int* __restrict__ within, const int* __restrict__ boff,
                        int* __restrict__ row_start, int* __restrict__ cursor, int n) {
    int i = blockIdx.x * 256 + threadIdx.x;
    if (i >= n) return;
    int v = within[i] + boff[i >> 9];
    row_start[i] = v;
    cursor[i]    = v;
}

__global__ void fill_k(const int* __restrict__ src, const int* __restrict__ dst,
                       const float* __restrict__ dinv, int* __restrict__ cursor,
                       int* __restrict__ eidx, float* __restrict__ ew, int E) {
    int e = blockIdx.x * 256 + threadIdx.x;
    if (e >= E) return;
    int s = src[e], d = dst[e];
    if (s == d) return;
    int pos = atomicAdd(&cursor[d], 1);
    eidx[pos] = s;
    ew[pos]   = dinv[s] * dinv[d];
}

// ---------------- MFMA GEMM: C[M,NC] = A[M,K] * W[NC,K]^T ----------------
// f16 inputs (converted in staging), f32 accumulate, f16 out.
// Block: 256 thr = 4 waves; tile 64 x NC (wave w: rows w*16..w*16+15, all NC).
// K-chunk 64. LDS rows 128 B, XOR-swizzled (byte ^= (row&7)<<4): fragment
// ds_read_b128 is 2-way max (free per m136).

template <int NC, bool A_IS_F32>
__global__ __launch_bounds__(256) void mgemm_k(const void* __restrict__ Av,
                                               const float* __restrict__ W,
                                               _Float16* __restrict__ C,
                                               int M, int K) {
    constexpr int CT = NC / 16;            // col tiles per wave
    __shared__ __align__(16) _Float16 As[64 * 64];
    __shared__ __align__(16) _Float16 Ws[NC * 64];

    const int tid  = threadIdx.x;
    const int lane = tid & 63, wave = tid >> 6;
    const int lrow = lane & 15, kg = lane >> 4;
    const int row0 = blockIdx.x * 64;

    f32x4 acc[CT] = {};

    const int nchunk = (K + 63) >> 6;
    for (int c0 = 0; c0 < nchunk; ++c0) {
        const int k0 = c0 * 64;
        // ---- stage A tile (64 x 64) ----
        if constexpr (A_IS_F32) {
            const float* A = (const float*)Av;
            #pragma unroll
            for (int it = 0; it < 4; ++it) {
                int idx  = tid + it * 256;
                int row  = idx >> 4, slot = idx & 15;     // 16 float4 slots/row
                int gr   = row0 + row, gk = k0 + slot * 4;
                float4 v = make_float4(0.f, 0.f, 0.f, 0.f);
                if (gr < M && gk < K)                      // K%4==0 -> all-or-none
                    v = *(const float4*)(A + (size_t)gr * K + gk);
                f16x4 h;
                h[0] = (_Float16)v.x; h[1] = (_Float16)v.y;
                h[2] = (_Float16)v.z; h[3] = (_Float16)v.w;
                int cb = (slot * 8) ^ ((row & 7) << 4);
                *(f16x4*)((char*)As + row * 128 + cb) = h;
            }
        } else {
            const _Float16* A = (const _Float16*)Av;
            #pragma unroll
            for (int it = 0; it < 2; ++it) {
                int idx = tid + it * 256;
                int row = idx >> 3, slot = idx & 7;        // 8x 16B slots/row
                int gr  = row0 + row, gk = k0 + slot * 8;
                uint4 v = make_uint4(0u, 0u, 0u, 0u);
                if (gr < M && gk < K)
                    v = *(const uint4*)(A + (size_t)gr * K + gk);
                int cb = (slot * 16) ^ ((row & 7) << 4);
                *(uint4*)((char*)As + row * 128 + cb) = v;
            }
        }
        // ---- stage W tile (NC x 64), W is f32 [NC][K] ----
        #pragma unroll
        for (int it = 0; it < NC / 16; ++it) {
            int idx = tid + it * 256;
            int row = idx >> 4, slot = idx & 15;
            int gk  = k0 + slot * 4;
            float4 v = make_float4(0.f, 0.f, 0.f, 0.f);
            if (gk < K)
                v = *(const float4*)(W + (size_t)row * K + gk);
            f16x4 h;
            h[0] = (_Float16)v.x; h[1] = (_Float16)v.y;
            h[2] = (_Float16)v.z; h[3] = (_Float16)v.w;
            int cb = (slot * 8) ^ ((row & 7) << 4);
            *(f16x4*)((char*)Ws + row * 128 + cb) = h;
        }
        __syncthreads();

        #pragma unroll
        for (int ks = 0; ks < 2; ++ks) {
            const int cbase = ks * 64 + kg * 16;
            f16x8 af, bf[CT];
            {
                int row = wave * 16 + lrow;
                af = *(const f16x8*)((const char*)As + row * 128 +
                                     (cbase ^ ((row & 7) << 4)));
            }
            #pragma unroll
            for (int ct = 0; ct < CT; ++ct) {
                int row = ct * 16 + lrow;
                bf[ct] = *(const f16x8*)((const char*)Ws + row * 128 +
                                         (cbase ^ ((row & 7) << 4)));
            }
            #pragma unroll
            for (int ct = 0; ct < CT; ++ct)
                acc[ct] = __builtin_amdgcn_mfma_f32_16x16x32_f16(
                    af, bf[ct], acc[ct], 0, 0, 0);
        }
        __syncthreads();
    }

    // ---- epilogue: D lane map col=lane&15, row=(lane>>4)*4+r ----
    #pragma unroll
    for (int r = 0; r < 4; ++r) {
        int grow = row0 + wave * 16 + kg * 4 + r;
        if (grow >= M) continue;
        #pragma unroll
        for (int ct = 0; ct < CT; ++ct)
            C[(size_t)grow * NC + ct * 16 + lrow] = (_Float16)acc[ct][r];
    }
}

// ---------------- GCN aggregation (gather over CSR, f16 rows) ----------------
// out[i] = sum_{e: dst=i} w_e * h[src_e] + invdeg[i]*h[i] + bias
// One wave per node, 4 nodes per 256-thread block.

template <int NF>
__global__ void agg_k(const _Float16* __restrict__ h, const float* __restrict__ invdeg,
                      const int* __restrict__ row_start, const int* __restrict__ cnt,
                      const int* __restrict__ eidx, const float* __restrict__ ew,
                      const float* __restrict__ bias, float* __restrict__ out, int n) {
    const int wv = threadIdx.x >> 6, lane = threadIdx.x & 63;
    const int i = blockIdx.x * 4 + wv;
    if (i >= n) return;
    const int st = row_start[i], en = st + cnt[i];
    const float id = invdeg[i];

    if constexpr (NF == 128) {
        const int c = lane * 2;
        f16x2 hv = *(const f16x2*)(h + (size_t)i * 128 + c);
        float a0 = fmaf(id, (float)hv[0], bias[c]);
        float a1 = fmaf(id, (float)hv[1], bias[c + 1]);
        int p = st;
        for (; p + 1 < en; p += 2) {
            int s0 = eidx[p], s1 = eidx[p + 1];
            float w0 = ew[p], w1 = ew[p + 1];
            f16x2 v0 = *(const f16x2*)(h + (size_t)s0 * 128 + c);
            f16x2 v1 = *(const f16x2*)(h + (size_t)s1 * 128 + c);
            a0 = fmaf(w0, (float)v0[0], a0); a1 = fmaf(w0, (float)v0[1], a1);
            a0 = fmaf(w1, (float)v1[0], a0); a1 = fmaf(w1, (float)v1[1], a1);
        }
        if (p < en) {
            int s0 = eidx[p]; float w0 = ew[p];
            f16x2 v0 = *(const f16x2*)(h + (size_t)s0 * 128 + c);
            a0 = fmaf(w0, (float)v0[0], a0); a1 = fmaf(w0, (float)v0[1], a1);
        }
        out[(size_t)i * 128 + c]     = a0;
        out[(size_t)i * 128 + c + 1] = a1;
    } else {
        float a0 = fmaf(id, (float)h[(size_t)i * NF + lane], bias[lane]);
        int p = st;
        for (; p + 1 < en; p += 2) {
            int s0 = eidx[p], s1 = eidx[p + 1];
            float w0 = ew[p], w1 = ew[p + 1];
            float v0 = (float)h[(size_t)s0 * NF + lane];
            float v1 = (float)h[(size_t)s1 * NF + lane];
            a0 = fmaf(w0, v0, a0);
            a0 = fmaf(w1, v1, a0);
        }
        if (p < en) {
            a0 = fmaf(ew[p], (float)h[(size_t)eidx[p] * NF + lane], a0);
        }
        out[(size_t)i * NF + lane] = a0;
    }
}

// ---------------- BatchNorm (affine=False) + ReLU ----------------

__global__ void stats_k(const float* __restrict__ a, float* __restrict__ gsum,
                        float* __restrict__ gsq, int n) {
    __shared__ float ls[256], lq[256];
    int tid = threadIdx.x;
    int c = tid & 127, g = tid >> 7;
    float s = 0.f, q = 0.f;
    for (int row = blockIdx.x * 2 + g; row < n; row += gridDim.x * 2) {
        float v = a[row * 128 + c];
        s += v; q += v * v;
    }
    ls[tid] = s; lq[tid] = q;
    __syncthreads();
    if (tid < 128) {
        atomicAdd(&gsum[c], ls[tid] + ls[tid + 128]);
        atomicAdd(&gsq[c],  lq[tid] + lq[tid + 128]);
    }
}

__global__ void finalize_k(const float* __restrict__ gsum, const float* __restrict__ gsq,
                           float* __restrict__ scale, float* __restrict__ shift, int n) {
    int c = threadIdx.x;   // 128
    float mean = gsum[c] / (float)n;
    float var  = gsq[c] / (float)n - mean * mean;
    float sc   = rsqrtf(var + EPS_BN);
    scale[c] = sc;
    shift[c] = -mean * sc;
}

// BN scale/shift + ReLU, f32 in -> f16 out (only consumer is the next GEMM)
__global__ void norm_k(const float* __restrict__ a, _Float16* __restrict__ o,
                       const float* __restrict__ scale, const float* __restrict__ shift,
                       int total4) {
    int idx = blockIdx.x * 256 + threadIdx.x;
    if (idx >= total4) return;
    float4 v = ((const float4*)a)[idx];
    int c0 = (idx & 31) * 4;
    f16x4 h;
    h[0] = (_Float16)fmaxf(0.f, fmaf(v.x, scale[c0 + 0], shift[c0 + 0]));
    h[1] = (_Float16)fmaxf(0.f, fmaf(v.y, scale[c0 + 1], shift[c0 + 1]));
    h[2] = (_Float16)fmaxf(0.f, fmaf(v.z, scale[c0 + 2], shift[c0 + 2]));
    h[3] = (_Float16)fmaxf(0.f, fmaf(v.w, scale[c0 + 3], shift[c0 + 3]));
    *(f16x4*)(o + (size_t)idx * 4) = h;
}

// ---------------- log_softmax over 64 cols: one wave per row ----------------

__global__ void lsm_k(float* __restrict__ out, int n) {
    int lane = threadIdx.x & 63;
    int row = blockIdx.x * 4 + (threadIdx.x >> 6);
    if (row >= n) return;
    float v = out[row * 64 + lane];
    float m = v;
    #pragma unroll
    for (int d = 32; d >= 1; d >>= 1) m = fmaxf(m, __shfl_xor(m, d, 64));
    float e = __expf(v - m);
    float s = e;
    #pragma unroll
    for (int d = 32; d >= 1; d >>= 1) s += __shfl_xor(s, d, 64);
    out[row * 64 + lane] = v - m - __logf(s);
}

// ---------------------------------------------------------------------------

extern "C" void kernel_launch(void* const* d_in, const int* in_sizes, int n_in,
                              void* d_out, int out_size, void* d_ws, size_t ws_size,
                              hipStream_t stream) {
    const float* x  = (const float*)d_in[0];
    const int*   ei = (const int*)d_in[1];
    const float* W0 = (const float*)d_in[2];
    const float* b0 = (const float*)d_in[3];
    const float* W1 = (const float*)d_in[4];
    const float* b1 = (const float*)d_in[5];
    const float* W2 = (const float*)d_in[6];
    const float* b2 = (const float*)d_in[7];

    const int IN = 500;
    const int n = in_sizes[0] / IN;      // 50000
    const int E = in_sizes[1] / 2;       // 640000
    const int* src = ei;
    const int* dst = ei + E;

    // ---- workspace bump allocator (256B aligned) ----
    char* p = (char*)d_ws;
    auto alloc = [&](size_t bytes) -> void* {
        char* r = p;
        p += (bytes + 255) & ~(size_t)255;
        return (void*)r;
    };
    _Float16*  hb1h    = (_Float16*)alloc((size_t)n * 128 * 2); // GEMM out / agg in
    float*     hb2     = (float*)alloc((size_t)n * 128 * 4);    // agg out / BN in
    _Float16*  hb2h    = (_Float16*)alloc((size_t)n * 128 * 2); // BN out / GEMM in
    int*   deg_cnt  = (int*)alloc((size_t)n * 4);
    float* dinv     = (float*)alloc((size_t)n * 4);
    float* invdeg   = (float*)alloc((size_t)n * 4);
    int*   row_st   = (int*)alloc((size_t)n * 4);
    int*   cursor   = (int*)alloc((size_t)n * 4);
    int*   within   = (int*)alloc((size_t)n * 4);
    int*   btot     = (int*)alloc(256 * 4);
    int*   boff     = (int*)alloc(256 * 4);
    int*   eidx     = (int*)alloc((size_t)E * 4);
    float* ew       = (float*)alloc((size_t)E * 4);
    float* gsum     = (float*)alloc(128 * 4);   // gsum+gsq contiguous: one memset
    float* gsq      = (float*)alloc(128 * 4);
    float* scale    = (float*)alloc(128 * 4);
    float* shift    = (float*)alloc(128 * 4);
    (void)ws_size; (void)n_in; (void)out_size;

    float* out = (float*)d_out;

    const int gE = (E + 255) / 256;
    const int gN = (n + 255) / 256;
    const int nblk = (n + 511) / 512;
    const int gM = (n + 63) / 64;        // 782 blocks
    const int gA = (n + 3) / 4;          // 12500 blocks

    // ---- graph prep (once per call) ----
    hipMemsetAsync(deg_cnt, 0, (size_t)n * 4, stream);
    count_k<<<gE, 256, 0, stream>>>(src, dst, deg_cnt, E);
    prep_k<<<gN, 256, 0, stream>>>(deg_cnt, dinv, invdeg, n);
    scan1_k<<<nblk, 512, 0, stream>>>(deg_cnt, within, btot, n);
    scan2_k<<<1, 64, 0, stream>>>(btot, boff, nblk);
    scan3_k<<<gN, 256, 0, stream>>>(within, boff, row_st, cursor, n);
    fill_k<<<gE, 256, 0, stream>>>(src, dst, dinv, cursor, eidx, ew, E);

    // ---- layer 0 ----
    mgemm_k<128, true><<<gM, 256, 0, stream>>>(x, W0, hb1h, n, IN);
    agg_k<128><<<gA, 256, 0, stream>>>(hb1h, invdeg, row_st, deg_cnt, eidx, ew, b0, hb2, n);
    hipMemsetAsync(gsum, 0, 256 * 4, stream);
    stats_k<<<256, 256, 0, stream>>>(hb2, gsum, gsq, n);
    finalize_k<<<1, 128, 0, stream>>>(gsum, gsq, scale, shift, n);
    norm_k<<<(n * 32 + 255) / 256, 256, 0, stream>>>(hb2, hb2h, scale, shift, n * 32);

    // ---- layer 1 ----
    mgemm_k<128, false><<<gM, 256, 0, stream>>>(hb2h, W1, hb1h, n, 128);
    agg_k<128><<<gA, 256, 0, stream>>>(hb1h, invdeg, row_st, deg_cnt, eidx, ew, b1, hb2, n);
    hipMemsetAsync(gsum, 0, 256 * 4, stream);
    stats_k<<<256, 256, 0, stream>>>(hb2, gsum, gsq, n);
    finalize_k<<<1, 128, 0, stream>>>(gsum, gsq, scale, shift, n);
    norm_k<<<(n * 32 + 255) / 256, 256, 0, stream>>>(hb2, hb2h, scale, shift, n * 32);

    // ---- classifier ----
    mgemm_k<64, false><<<gM, 256, 0, stream>>>(hb2h, W2, hb1h, n, 128);
    agg_k<64><<<gA, 256, 0, stream>>>(hb1h, invdeg, row_st, deg_cnt, eidx, ew, b2, out, n);
    lsm_k<<<(n + 3) / 4, 256, 0, stream>>>(out, n);
}

// Round 4
// 321.119 us; speedup vs baseline: 2.2059x; 1.1153x over previous
//
#include <hip/hip_runtime.h>
#include <hip/hip_bf16.h>
#include <math.h>

// ---------------------------------------------------------------------------
// PMLP_GCN forward:  3x (GEMM -> GCN-agg[+bias]) with BN+ReLU between,
// log_softmax at the end.  N=50000 E=640000 IN=500 HID=128 OUT=64, f32.
// R3: GEMM K-loop double-buffered (reg-staged prefetch, 1 barrier/iter);
//     log_softmax fused into agg64; agg128 4-edge unroll.
// ---------------------------------------------------------------------------

#define EPS_BN 1e-5f

typedef __attribute__((ext_vector_type(8))) _Float16 f16x8;
typedef __attribute__((ext_vector_type(4))) _Float16 f16x4;
typedef __attribute__((ext_vector_type(2))) _Float16 f16x2;
typedef __attribute__((ext_vector_type(4))) float    f32x4;

// ---------------- graph prep ----------------

__global__ void count_k(const int* __restrict__ src, const int* __restrict__ dst,
                        int* __restrict__ cnt, int E) {
    int e = blockIdx.x * 256 + threadIdx.x;
    if (e >= E) return;
    int s = src[e], d = dst[e];
    if (s != d) atomicAdd(&cnt[d], 1);
}

__global__ void prep_k(const int* __restrict__ cnt, float* __restrict__ dinv,
                       float* __restrict__ invdeg, int n) {
    int i = blockIdx.x * 256 + threadIdx.x;
    if (i >= n) return;
    float deg = (float)cnt[i] + 1.0f;   // +1 for added self loop
    dinv[i]   = rsqrtf(deg);
    invdeg[i] = 1.0f / deg;
}

// 3-kernel exclusive prefix scan over cnt[n] -> row_start
__global__ void scan1_k(const int* __restrict__ cnt, int* __restrict__ within,
                        int* __restrict__ btot, int n) {
    __shared__ int s[512];
    int tid = threadIdx.x;
    int i = blockIdx.x * 512 + tid;
    int val = (i < n) ? cnt[i] : 0;
    s[tid] = val;
    __syncthreads();
    for (int off = 1; off < 512; off <<= 1) {
        int v = (tid >= off) ? s[tid - off] : 0;
        __syncthreads();
        s[tid] += v;
        __syncthreads();
    }
    if (i < n) within[i] = s[tid] - val;   // exclusive
    if (tid == 511) btot[blockIdx.x] = s[511];
}

__global__ void scan2_k(const int* __restrict__ btot, int* __restrict__ boff, int nblk) {
    if (threadIdx.x == 0) {
        int run = 0;
        for (int b = 0; b < nblk; ++b) { boff[b] = run; run += btot[b]; }
    }
}

__global__ void scan3_k(const int* __restrict__ within, const int* __restrict__ boff,
                        int* __restrict__ row_start, int* __restrict__ cursor, int n) {
    int i = blockIdx.x * 256 + threadIdx.x;
    if (i >= n) return;
    int v = within[i] + boff[i >> 9];
    row_start[i] = v;
    cursor[i]    = v;
}

__global__ void fill_k(const int* __restrict__ src, const int* __restrict__ dst,
                       const float* __restrict__ dinv, int* __restrict__ cursor,
                       int* __restrict__ eidx, float* __restrict__ ew, int E) {
    int e = blockIdx.x * 256 + threadIdx.x;
    if (e >= E) return;
    int s = src[e], d = dst[e];
    if (s == d) return;
    int pos = atomicAdd(&cursor[d], 1);
    eidx[pos] = s;
    ew[pos]   = dinv[s] * dinv[d];
}

// ---------------- MFMA GEMM: C[M,NC] = A[M,K] * W[NC,K]^T ----------------
// f16 inputs (converted in staging), f32 accumulate, f16 out.
// Block: 256 thr = 4 waves; tile 64 x NC; K-chunk 64; DOUBLE-BUFFERED:
// iter c issues chunk c+1 global loads to regs, computes chunk c from LDS,
// then converts+writes chunk c+1 and barriers (1 barrier/iter; buffer parity
// alternates so write-vs-read races are separated by the previous barrier).
// LDS rows 128 B, XOR-swizzled (byte ^= (row&7)<<4): ds_read_b128 2-way max.

template <int NC, bool A_IS_F32>
__global__ __launch_bounds__(256) void mgemm_k(const void* __restrict__ Av,
                                               const float* __restrict__ W,
                                               _Float16* __restrict__ C,
                                               int M, int K) {
    constexpr int CT = NC / 16;            // col frags per wave
    constexpr int WI = NC / 16;            // W float4 loads per thread
    __shared__ __align__(16) _Float16 As[2][64 * 64];
    __shared__ __align__(16) _Float16 Ws[2][NC * 64];

    const int tid  = threadIdx.x;
    const int lane = tid & 63, wave = tid >> 6;
    const int lrow = lane & 15, kg = lane >> 4;
    const int row0 = blockIdx.x * 64;

    f32x4 acc[CT] = {};

    float4 aw[4];          // A prefetch regs (f32 path)
    uint4  ah[2];          // A prefetch regs (f16 path)
    float4 ww[WI];         // W prefetch regs

    auto load_regs = [&](int c0) {
        const int k0 = c0 * 64;
        if constexpr (A_IS_F32) {
            const float* A = (const float*)Av;
            #pragma unroll
            for (int it = 0; it < 4; ++it) {
                int idx = tid + it * 256;
                int row = idx >> 4, slot = idx & 15;      // 16 float4/row
                int gr = row0 + row, gk = k0 + slot * 4;
                aw[it] = make_float4(0.f, 0.f, 0.f, 0.f);
                if (gr < M && gk < K)                      // K%4==0
                    aw[it] = *(const float4*)(A + (size_t)gr * K + gk);
            }
        } else {
            const _Float16* A = (const _Float16*)Av;
            #pragma unroll
            for (int it = 0; it < 2; ++it) {
                int idx = tid + it * 256;
                int row = idx >> 3, slot = idx & 7;        // 8x 16B/row
                int gr = row0 + row, gk = k0 + slot * 8;
                ah[it] = make_uint4(0u, 0u, 0u, 0u);
                if (gr < M && gk < K)
                    ah[it] = *(const uint4*)(A + (size_t)gr * K + gk);
            }
        }
        #pragma unroll
        for (int it = 0; it < WI; ++it) {
            int idx = tid + it * 256;
            int row = idx >> 4, slot = idx & 15;
            int gk = k0 + slot * 4;
            ww[it] = make_float4(0.f, 0.f, 0.f, 0.f);
            if (gk < K)
                ww[it] = *(const float4*)(W + (size_t)row * K + gk);
        }
    };

    auto write_lds = [&](int b) {
        if constexpr (A_IS_F32) {
            #pragma unroll
            for (int it = 0; it < 4; ++it) {
                int idx = tid + it * 256;
                int row = idx >> 4, slot = idx & 15;
                f16x4 h;
                h[0] = (_Float16)aw[it].x; h[1] = (_Float16)aw[it].y;
                h[2] = (_Float16)aw[it].z; h[3] = (_Float16)aw[it].w;
                int cb = (slot * 8) ^ ((row & 7) << 4);
                *(f16x4*)((char*)As[b] + row * 128 + cb) = h;
            }
        } else {
            #pragma unroll
            for (int it = 0; it < 2; ++it) {
                int idx = tid + it * 256;
                int row = idx >> 3, slot = idx & 7;
                int cb = (slot * 16) ^ ((row & 7) << 4);
                *(uint4*)((char*)As[b] + row * 128 + cb) = ah[it];
            }
        }
        #pragma unroll
        for (int it = 0; it < WI; ++it) {
            int idx = tid + it * 256;
            int row = idx >> 4, slot = idx & 15;
            f16x4 h;
            h[0] = (_Float16)ww[it].x; h[1] = (_Float16)ww[it].y;
            h[2] = (_Float16)ww[it].z; h[3] = (_Float16)ww[it].w;
            int cb = (slot * 8) ^ ((row & 7) << 4);
            *(f16x4*)((char*)Ws[b] + row * 128 + cb) = h;
        }
    };

    auto compute = [&](int b) {
        #pragma unroll
        for (int ks = 0; ks < 2; ++ks) {
            const int cbase = ks * 64 + kg * 16;
            f16x8 af, bf[CT];
            {
                int row = wave * 16 + lrow;
                af = *(const f16x8*)((const char*)As[b] + row * 128 +
                                     (cbase ^ ((row & 7) << 4)));
            }
            #pragma unroll
            for (int ct = 0; ct < CT; ++ct) {
                int row = ct * 16 + lrow;
                bf[ct] = *(const f16x8*)((const char*)Ws[b] + row * 128 +
                                         (cbase ^ ((row & 7) << 4)));
            }
            #pragma unroll
            for (int ct = 0; ct < CT; ++ct)
                acc[ct] = __builtin_amdgcn_mfma_f32_16x16x32_f16(
                    af, bf[ct], acc[ct], 0, 0, 0);
        }
    };

    const int nchunk = (K + 63) >> 6;
    // prologue: stage chunk 0
    load_regs(0);
    write_lds(0);
    __syncthreads();
    for (int c = 0; c < nchunk; ++c) {
        const int b = c & 1;
        const bool more = (c + 1 < nchunk);
        if (more) load_regs(c + 1);     // issue loads; land during compute
        compute(b);
        if (more) {
            write_lds(b ^ 1);
            __syncthreads();
        }
    }

    // ---- epilogue: D lane map col=lane&15, row=(lane>>4)*4+r ----
    #pragma unroll
    for (int r = 0; r < 4; ++r) {
        int grow = row0 + wave * 16 + kg * 4 + r;
        if (grow >= M) continue;
        #pragma unroll
        for (int ct = 0; ct < CT; ++ct)
            C[(size_t)grow * NC + ct * 16 + lrow] = (_Float16)acc[ct][r];
    }
}

// ---------------- GCN aggregation (gather over CSR, f16 rows) ----------------
// out[i] = sum_{e: dst=i} w_e * h[src_e] + invdeg[i]*h[i] + bias
// One wave per node, 4 nodes per 256-thread block, 4-edge unroll.

__global__ void agg128_k(const _Float16* __restrict__ h, const float* __restrict__ invdeg,
                         const int* __restrict__ row_start, const int* __restrict__ cnt,
                         const int* __restrict__ eidx, const float* __restrict__ ew,
                         const float* __restrict__ bias, float* __restrict__ out, int n) {
    const int wv = threadIdx.x >> 6, lane = threadIdx.x & 63;
    const int i = blockIdx.x * 4 + wv;
    if (i >= n) return;
    const int st = row_start[i], en = st + cnt[i];
    const float id = invdeg[i];
    const int c = lane * 2;

    f16x2 hv = *(const f16x2*)(h + (size_t)i * 128 + c);
    float a0 = fmaf(id, (float)hv[0], bias[c]);
    float a1 = fmaf(id, (float)hv[1], bias[c + 1]);
    int p = st;
    for (; p + 3 < en; p += 4) {
        int s0 = eidx[p], s1 = eidx[p + 1], s2 = eidx[p + 2], s3 = eidx[p + 3];
        float w0 = ew[p], w1 = ew[p + 1], w2 = ew[p + 2], w3 = ew[p + 3];
        f16x2 v0 = *(const f16x2*)(h + (size_t)s0 * 128 + c);
        f16x2 v1 = *(const f16x2*)(h + (size_t)s1 * 128 + c);
        f16x2 v2 = *(const f16x2*)(h + (size_t)s2 * 128 + c);
        f16x2 v3 = *(const f16x2*)(h + (size_t)s3 * 128 + c);
        a0 = fmaf(w0, (float)v0[0], a0); a1 = fmaf(w0, (float)v0[1], a1);
        a0 = fmaf(w1, (float)v1[0], a0); a1 = fmaf(w1, (float)v1[1], a1);
        a0 = fmaf(w2, (float)v2[0], a0); a1 = fmaf(w2, (float)v2[1], a1);
        a0 = fmaf(w3, (float)v3[0], a0); a1 = fmaf(w3, (float)v3[1], a1);
    }
    for (; p < en; ++p) {
        int s0 = eidx[p]; float w0 = ew[p];
        f16x2 v0 = *(const f16x2*)(h + (size_t)s0 * 128 + c);
        a0 = fmaf(w0, (float)v0[0], a0); a1 = fmaf(w0, (float)v0[1], a1);
    }
    out[(size_t)i * 128 + c]     = a0;
    out[(size_t)i * 128 + c + 1] = a1;
}

// ---- classifier agg (64 cols) with log_softmax fused (row == wave) ----

__global__ void aggsm_k(const _Float16* __restrict__ h, const float* __restrict__ invdeg,
                        const int* __restrict__ row_start, const int* __restrict__ cnt,
                        const int* __restrict__ eidx, const float* __restrict__ ew,
                        const float* __restrict__ bias, float* __restrict__ out, int n) {
    const int wv = threadIdx.x >> 6, lane = threadIdx.x & 63;
    const int i = blockIdx.x * 4 + wv;
    if (i >= n) return;
    const int st = row_start[i], en = st + cnt[i];
    const float id = invdeg[i];

    float a0 = fmaf(id, (float)h[(size_t)i * 64 + lane], bias[lane]);
    int p = st;
    for (; p + 3 < en; p += 4) {
        int s0 = eidx[p], s1 = eidx[p + 1], s2 = eidx[p + 2], s3 = eidx[p + 3];
        float w0 = ew[p], w1 = ew[p + 1], w2 = ew[p + 2], w3 = ew[p + 3];
        float v0 = (float)h[(size_t)s0 * 64 + lane];
        float v1 = (float)h[(size_t)s1 * 64 + lane];
        float v2 = (float)h[(size_t)s2 * 64 + lane];
        float v3 = (float)h[(size_t)s3 * 64 + lane];
        a0 = fmaf(w0, v0, a0); a0 = fmaf(w1, v1, a0);
        a0 = fmaf(w2, v2, a0); a0 = fmaf(w3, v3, a0);
    }
    for (; p < en; ++p)
        a0 = fmaf(ew[p], (float)h[(size_t)eidx[p] * 64 + lane], a0);

    // fused log_softmax over the 64-wide row held by this wave
    float m = a0;
    #pragma unroll
    for (int d = 32; d >= 1; d >>= 1) m = fmaxf(m, __shfl_xor(m, d, 64));
    float e = __expf(a0 - m);
    float s = e;
    #pragma unroll
    for (int d = 32; d >= 1; d >>= 1) s += __shfl_xor(s, d, 64);
    out[(size_t)i * 64 + lane] = a0 - m - __logf(s);
}

// ---------------- BatchNorm (affine=False) + ReLU ----------------

__global__ void stats_k(const float* __restrict__ a, float* __restrict__ gsum,
                        float* __restrict__ gsq, int n) {
    __shared__ float ls[256], lq[256];
    int tid = threadIdx.x;
    int c = tid & 127, g = tid >> 7;
    float s = 0.f, q = 0.f;
    for (int row = blockIdx.x * 2 + g; row < n; row += gridDim.x * 2) {
        float v = a[row * 128 + c];
        s += v; q += v * v;
    }
    ls[tid] = s; lq[tid] = q;
    __syncthreads();
    if (tid < 128) {
        atomicAdd(&gsum[c], ls[tid] + ls[tid + 128]);
        atomicAdd(&gsq[c],  lq[tid] + lq[tid + 128]);
    }
}

__global__ void finalize_k(const float* __restrict__ gsum, const float* __restrict__ gsq,
                           float* __restrict__ scale, float* __restrict__ shift, int n) {
    int c = threadIdx.x;   // 128
    float mean = gsum[c] / (float)n;
    float var  = gsq[c] / (float)n - mean * mean;
    float sc   = rsqrtf(var + EPS_BN);
    scale[c] = sc;
    shift[c] = -mean * sc;
}

// BN scale/shift + ReLU, f32 in -> f16 out (only consumer is the next GEMM)
__global__ void norm_k(const float* __restrict__ a, _Float16* __restrict__ o,
                       const float* __restrict__ scale, const float* __restrict__ shift,
                       int total4) {
    int idx = blockIdx.x * 256 + threadIdx.x;
    if (idx >= total4) return;
    float4 v = ((const float4*)a)[idx];
    int c0 = (idx & 31) * 4;
    f16x4 h;
    h[0] = (_Float16)fmaxf(0.f, fmaf(v.x, scale[c0 + 0], shift[c0 + 0]));
    h[1] = (_Float16)fmaxf(0.f, fmaf(v.y, scale[c0 + 1], shift[c0 + 1]));
    h[2] = (_Float16)fmaxf(0.f, fmaf(v.z, scale[c0 + 2], shift[c0 + 2]));
    h[3] = (_Float16)fmaxf(0.f, fmaf(v.w, scale[c0 + 3], shift[c0 + 3]));
    *(f16x4*)(o + (size_t)idx * 4) = h;
}

// ---------------------------------------------------------------------------

extern "C" void kernel_launch(void* const* d_in, const int* in_sizes, int n_in,
                              void* d_out, int out_size, void* d_ws, size_t ws_size,
                              hipStream_t stream) {
    const float* x  = (const float*)d_in[0];
    const int*   ei = (const int*)d_in[1];
    const float* W0 = (const float*)d_in[2];
    const float* b0 = (const float*)d_in[3];
    const float* W1 = (const float*)d_in[4];
    const float* b1 = (const float*)d_in[5];
    const float* W2 = (const float*)d_in[6];
    const float* b2 = (const float*)d_in[7];

    const int IN = 500;
    const int n = in_sizes[0] / IN;      // 50000
    const int E = in_sizes[1] / 2;       // 640000
    const int* src = ei;
    const int* dst = ei + E;

    // ---- workspace bump allocator (256B aligned) ----
    char* p = (char*)d_ws;
    auto alloc = [&](size_t bytes) -> void* {
        char* r = p;
        p += (bytes + 255) & ~(size_t)255;
        return (void*)r;
    };
    _Float16*  hb1h    = (_Float16*)alloc((size_t)n * 128 * 2); // GEMM out / agg in
    float*     hb2     = (float*)alloc((size_t)n * 128 * 4);    // agg out / BN in
    _Float16*  hb2h    = (_Float16*)alloc((size_t)n * 128 * 2); // BN out / GEMM in
    int*   deg_cnt  = (int*)alloc((size_t)n * 4);
    float* dinv     = (float*)alloc((size_t)n * 4);
    float* invdeg   = (float*)alloc((size_t)n * 4);
    int*   row_st   = (int*)alloc((size_t)n * 4);
    int*   cursor   = (int*)alloc((size_t)n * 4);
    int*   within   = (int*)alloc((size_t)n * 4);
    int*   btot     = (int*)alloc(256 * 4);
    int*   boff     = (int*)alloc(256 * 4);
    int*   eidx     = (int*)alloc((size_t)E * 4);
    float* ew       = (float*)alloc((size_t)E * 4);
    float* gsum     = (float*)alloc(128 * 4);   // gsum+gsq contiguous: one memset
    float* gsq      = (float*)alloc(128 * 4);
    float* scale    = (float*)alloc(128 * 4);
    float* shift    = (float*)alloc(128 * 4);
    (void)ws_size; (void)n_in; (void)out_size;

    float* out = (float*)d_out;

    const int gE = (E + 255) / 256;
    const int gN = (n + 255) / 256;
    const int nblk = (n + 511) / 512;
    const int gM = (n + 63) / 64;        // 782 blocks
    const int gA = (n + 3) / 4;          // 12500 blocks

    // ---- graph prep (once per call) ----
    hipMemsetAsync(deg_cnt, 0, (size_t)n * 4, stream);
    count_k<<<gE, 256, 0, stream>>>(src, dst, deg_cnt, E);
    prep_k<<<gN, 256, 0, stream>>>(deg_cnt, dinv, invdeg, n);
    scan1_k<<<nblk, 512, 0, stream>>>(deg_cnt, within, btot, n);
    scan2_k<<<1, 64, 0, stream>>>(btot, boff, nblk);
    scan3_k<<<gN, 256, 0, stream>>>(within, boff, row_st, cursor, n);
    fill_k<<<gE, 256, 0, stream>>>(src, dst, dinv, cursor, eidx, ew, E);

    // ---- layer 0 ----
    mgemm_k<128, true><<<gM, 256, 0, stream>>>(x, W0, hb1h, n, IN);
    agg128_k<<<gA, 256, 0, stream>>>(hb1h, invdeg, row_st, deg_cnt, eidx, ew, b0, hb2, n);
    hipMemsetAsync(gsum, 0, 256 * 4, stream);
    stats_k<<<256, 256, 0, stream>>>(hb2, gsum, gsq, n);
    finalize_k<<<1, 128, 0, stream>>>(gsum, gsq, scale, shift, n);
    norm_k<<<(n * 32 + 255) / 256, 256, 0, stream>>>(hb2, hb2h, scale, shift, n * 32);

    // ---- layer 1 ----
    mgemm_k<128, false><<<gM, 256, 0, stream>>>(hb2h, W1, hb1h, n, 128);
    agg128_k<<<gA, 256, 0, stream>>>(hb1h, invdeg, row_st, deg_cnt, eidx, ew, b1, hb2, n);
    hipMemsetAsync(gsum, 0, 256 * 4, stream);
    stats_k<<<256, 256, 0, stream>>>(hb2, gsum, gsq, n);
    finalize_k<<<1, 128, 0, stream>>>(gsum, gsq, scale, shift, n);
    norm_k<<<(n * 32 + 255) / 256, 256, 0, stream>>>(hb2, hb2h, scale, shift, n * 32);

    // ---- classifier (log_softmax fused into agg) ----
    mgemm_k<64, false><<<gM, 256, 0, stream>>>(hb2h, W2, hb1h, n, 128);
    aggsm_k<<<gA, 256, 0, stream>>>(hb1h, invdeg, row_st, deg_cnt, eidx, ew, b2, out, n);
}